// Round 7
// baseline (616.372 us; speedup 1.0000x reference)
//
#include <hip/hip_runtime.h>
#include <hip/hip_bf16.h>

// TDNN as GEMM: out[m,o] = relu(bias[o] + sum_kk A[m,kk]*W[kk,o])
//   A[m,kk] = x[b, t+kw, c] (contiguous 2560-elem slice of x)
// R7: R6 structure (128x128 tile, 4 waves, B fragment-native in regs from L2,
// counted vmcnt + 1 barrier per K-tile, 0-conflict XOR swizzle) with A LDS
// rotation cut to 3 buffers (48 KiB) -> 3 blocks/CU for cross-block
// MFMA/memory co-scheduling (m114 mechanism).

#define BATCH 64
#define SEQ   1000
#define CIN   512
#define COUT  512
#define TOUT  996
#define KTOT  2560
#define MTOT  63744
#define NKT   40            // K-tiles of 64
#define MT    498           // MTOT/128
#define NT    4             // COUT/128
#define NWG   (MT*NT)       // 1992 = 8*249

typedef __bf16 bf16x8 __attribute__((ext_vector_type(8)));
typedef float  f32x4  __attribute__((ext_vector_type(4)));

__device__ __forceinline__ void gload_lds16(const void* g, void* l) {
  __builtin_amdgcn_global_load_lds(
      (const __attribute__((address_space(1))) void*)g,
      (__attribute__((address_space(3))) void*)l, 16, 0, 0);
}

#define BAR()    __builtin_amdgcn_s_barrier()
#define VM12()   asm volatile("s_waitcnt vmcnt(12)" ::: "memory")
#define VM8()    asm volatile("s_waitcnt vmcnt(8)"  ::: "memory")
#define VM4()    asm volatile("s_waitcnt vmcnt(4)"  ::: "memory")
#define PRIO(x)  __builtin_amdgcn_s_setprio(x)
#define SCHED0() __builtin_amdgcn_sched_barrier(0)
#define MFMA(d, x, y) d = __builtin_amdgcn_mfma_f32_16x16x32_bf16(x, y, d, 0, 0, 0)

// ---- x fp32 -> bf16 ----
__global__ void cvt_x_kernel(const float* __restrict__ x, __bf16* __restrict__ xb, int n) {
  int i = (blockIdx.x * blockDim.x + threadIdx.x) * 8;
  if (i >= n) return;
  float4 f0 = *(const float4*)(x + i);
  float4 f1 = *(const float4*)(x + i + 4);
  bf16x8 v;
  v[0] = (__bf16)f0.x; v[1] = (__bf16)f0.y; v[2] = (__bf16)f0.z; v[3] = (__bf16)f0.w;
  v[4] = (__bf16)f1.x; v[5] = (__bf16)f1.y; v[6] = (__bf16)f1.z; v[7] = (__bf16)f1.w;
  *(bf16x8*)(xb + i) = v;
}

// ---- kernel [O][C][KW] fp32 -> Wt2 fragment-native bf16 ----
// elem idx = ((ks*32 + ob)*64 + l)*8 + j
//   col o = ob*16 + (l&15); k = ks*32 + ((l>>4)&3)*8 + j; c = k&511; kw = k>>9
__global__ void cvt_w_kernel(const float* __restrict__ k, __bf16* __restrict__ wt) {
  int idx = blockIdx.x * blockDim.x + threadIdx.x;   // 1,310,720
  if (idx >= 80 * 32 * 512) return;
  int j  = idx & 7;
  int l  = (idx >> 3) & 63;
  int t1 = idx >> 9;
  int ob = t1 & 31;
  int ks = t1 >> 5;
  int o  = ob * 16 + (l & 15);
  int kk = ks * 32 + ((l >> 4) & 3) * 8 + j;
  int c  = kk & 511, kw = kk >> 9;
  wt[idx] = (__bf16)k[(o * CIN + c) * 5 + kw];
}

// stage one A K-tile (128 rows x 64 bf16 = 16 KiB) into LDS buffer `buf`
#define STAGE(buf, kt) do { \
    char* d_ = (char*)Ab + ((buf) << 14); \
    gload_lds16(Xb + offA0 + (kt) * 64, d_ + dof0); \
    gload_lds16(Xb + offA1 + (kt) * 64, d_ + dof1); \
    gload_lds16(Xb + offA2 + (kt) * 64, d_ + dof2); \
    gload_lds16(Xb + offA3 + (kt) * 64, d_ + dof3); } while (0)

// load next-tile B fragments from global (L2-resident), 8 x dwordx4
#define LOADB(bn, Tn) do { \
    const char* p_ = Wglob + (size_t)(Tn) * 65536; \
    bn[0][0] = *(const bf16x8*)(p_ +     0); bn[0][1] = *(const bf16x8*)(p_ + 32768); \
    bn[1][0] = *(const bf16x8*)(p_ +  1024); bn[1][1] = *(const bf16x8*)(p_ + 33792); \
    bn[2][0] = *(const bf16x8*)(p_ +  2048); bn[2][1] = *(const bf16x8*)(p_ + 34816); \
    bn[3][0] = *(const bf16x8*)(p_ +  3072); bn[3][1] = *(const bf16x8*)(p_ + 35840); } while (0)

// one K-tile: prefetch B(T+1)->regs, stage A(T+2)->LDS buf `bufs`, compute
// from buf `bufc`; counted vmcnt + single barrier.
#define TILE(T, bc, bn, bufc, bufs) do { \
    const bool s1_ = (T) + 1 < NKT, s2_ = (T) + 2 < NKT; \
    if (s1_) LOADB(bn, (T) + 1); \
    if (s2_) STAGE(bufs, (T) + 2); \
    const char* Ac_ = Aw + ((bufc) << 14); \
    bf16x8 a_[4][2]; \
    _Pragma("unroll") \
    for (int mi = 0; mi < 4; ++mi) { \
      a_[mi][0] = *(const bf16x8*)(Ac_ + mi * 2048 + off0); \
      a_[mi][1] = *(const bf16x8*)(Ac_ + mi * 2048 + off1); \
    } \
    PRIO(1); \
    _Pragma("unroll") \
    for (int mi = 0; mi < 4; ++mi) \
      _Pragma("unroll") \
      for (int nj = 0; nj < 4; ++nj) { \
        MFMA(acc[mi][nj], a_[mi][0], bc[nj][0]); \
        MFMA(acc[mi][nj], a_[mi][1], bc[nj][1]); \
      } \
    PRIO(0); \
    SCHED0(); \
    if (s2_) { VM12(); } else if (s1_) { VM8(); } \
    if (s1_) BAR(); \
  } while (0)

__global__ __launch_bounds__(256, 3)
void tdnn_gemm_kernel(const __bf16* __restrict__ Xb, const __bf16* __restrict__ Wt2,
                      const float* __restrict__ bias, float* __restrict__ out) {
  // A only: 3 rotating K-tile buffers x 128 rows x 64 bf16 = 48 KiB -> 3 blocks/CU
  __shared__ __bf16 Ab[3][128][64];

  const int tid  = threadIdx.x;
  const int wave = tid >> 6;
  const int lane = tid & 63;
  const int wr = wave >> 1;          // 0..1 : 64-row band
  const int wc = wave & 1;           // 0..1 : 64-col band

  // bijective XCD swizzle: 1992 = 8*249; consecutive swz share the A-panel
  int bid = blockIdx.x;
  int swz = (bid & 7) * 249 + (bid >> 3);
  const int m0 = (swz >> 2) * 128;
  const int n0 = (swz & 3) * 128;

  // ---- A staging offsets (pre-swizzled global source, linear LDS dest)
  int offA0, offA1, offA2, offA3, dof0, dof1, dof2, dof3;
  {
    int rr, ce, m, b, tt;
#define MKOFF(l, A, D) \
    rr = (l) * 32 + (tid >> 3); \
    ce = (((tid & 7) ^ (rr & 7)) << 3); \
    D  = ((l) * 256 + tid) * 16; \
    m = m0 + rr; b = m / TOUT; tt = m - b * TOUT; \
    A = (b * SEQ + tt) * CIN + ce;
    MKOFF(0, offA0, dof0)
    MKOFF(1, offA1, dof1)
    MKOFF(2, offA2, dof2)
    MKOFF(3, offA3, dof3)
#undef MKOFF
  }

  // ---- fragment read geometry (A from LDS, T2 read-side XOR)
  const int frow = lane & 15;
  const int fkb  = (lane >> 4) << 4;        // 0,16,32,48 bytes
  const int xorv = (frow & 7) << 4;
  const int off0 = fkb ^ xorv;              // k-slice 0
  const int off1 = (64 + fkb) ^ xorv;       // k-slice 1
  const char* Aw = (const char*)Ab + (wr * 64 + frow) * 128;

  // ---- B fragment-native global base for this wave
  const int obW = (n0 >> 4) + wc * 4;
  const char* Wglob = (const char*)Wt2 + obW * 1024 + lane * 16;

  f32x4 acc[4][4];
  const f32x4 z = {0.f, 0.f, 0.f, 0.f};
#pragma unroll
  for (int i = 0; i < 4; i++)
#pragma unroll
    for (int j = 0; j < 4; j++) acc[i][j] = z;

  bf16x8 bA[4][2], bB[4][2];

  // ---- prologue: B(0)->bA, stage A(0)->buf0, A(1)->buf1; drain through A(0)
  LOADB(bA, 0);
  STAGE(0, 0);
  STAGE(1, 1);
  VM4();       // in-order: drains B(0)x8 + A(0)x4, leaves A(1)x4 in flight
  BAR();

  // buffer of tile T is T%3; rotate with scalar adds (no div)
  int bT = 0;
  for (int T = 0; T < NKT; T += 2) {
    int bT1 = bT + 1; if (bT1 == 3) bT1 = 0;   // (T+1)%3
    int bT2 = bT1 + 1; if (bT2 == 3) bT2 = 0;  // (T+2)%3
    TILE(T,     bA, bB, bT,  bT2);  // compute buf T%3,   stage (T+2)%3
    TILE(T + 1, bB, bA, bT1, bT);   // compute buf (T+1)%3, stage (T+3)%3 == bT
    bT = bT2;
  }

  // ---- epilogue: bias + relu + store. C/D map: col=lane&15, row=(lane>>4)*4+reg
  const int ccol = lane & 15;
  const int crow = (lane >> 4) * 4;
  float bv[4];
#pragma unroll
  for (int nj = 0; nj < 4; ++nj)
    bv[nj] = bias[n0 + wc * 64 + nj * 16 + ccol];

#pragma unroll
  for (int mi = 0; mi < 4; ++mi) {
    const int mrow = m0 + wr * 64 + mi * 16 + crow;
#pragma unroll
    for (int nj = 0; nj < 4; ++nj) {
      const int ocol = n0 + wc * 64 + nj * 16 + ccol;
#pragma unroll
      for (int j = 0; j < 4; ++j) {
        float v = acc[mi][nj][j] + bv[nj];
        v = v > 0.f ? v : 0.f;
        out[(size_t)(mrow + j) * COUT + ocol] = v;
      }
    }
  }
}

extern "C" void kernel_launch(void* const* d_in, const int* in_sizes, int n_in,
                              void* d_out, int out_size, void* d_ws, size_t ws_size,
                              hipStream_t stream) {
  const float* x      = (const float*)d_in[0];   // [64,1000,512] fp32
  const float* kernel = (const float*)d_in[1];   // [512,512,5]   fp32
  const float* bias   = (const float*)d_in[2];   // [512]         fp32
  float* out          = (float*)d_out;           // [64,996,512]  fp32

  __bf16* xb  = (__bf16*)d_ws;
  __bf16* wt2 = (__bf16*)((char*)d_ws + (size_t)BATCH * SEQ * CIN * 2);

  const int nx = BATCH * SEQ * CIN;              // 32,768,000
  cvt_x_kernel<<<nx / 8 / 256, 256, 0, stream>>>(x, xb, nx);
  cvt_w_kernel<<<(80 * 32 * 512 + 255) / 256, 256, 0, stream>>>(kernel, wt2);
  tdnn_gemm_kernel<<<NWG, 256, 0, stream>>>(xb, wt2, bias, out);
}

// Round 8
// 209.642 us; speedup vs baseline: 2.9401x; 2.9401x over previous
//
#include <hip/hip_runtime.h>
#include <hip/hip_bf16.h>

// TDNN as GEMM: out[m,o] = relu(bias[o] + sum_kk A[m,kk]*W[kk,o])
//   A[m,kk] = x[b, t+kw, c] (contiguous 2560-elem slice of x)
// R8: R6 structure exactly (128x128 tile, 4 waves, B fragment-native in regs
// from L2 double-buffered, counted vmcnt + 1 barrier per K-tile, 0-conflict
// XOR swizzle) with A LDS rotation cut to 3 buffers (48 KiB) via
// COMPILE-TIME buffer indices (6-tile unroll), launch_bounds kept at (256,2)
// so the allocator is NOT squeezed (R7 lesson: forcing 3 waves/EU -> spills).
// Hardware residency: min(LDS 160/48, VGPR 512/160) = 3 blocks/CU.

#define BATCH 64
#define SEQ   1000
#define CIN   512
#define COUT  512
#define TOUT  996
#define KTOT  2560
#define MTOT  63744
#define NKT   40            // K-tiles of 64
#define MT    498           // MTOT/128
#define NT    4             // COUT/128
#define NWG   (MT*NT)       // 1992 = 8*249

typedef __bf16 bf16x8 __attribute__((ext_vector_type(8)));
typedef float  f32x4  __attribute__((ext_vector_type(4)));

__device__ __forceinline__ void gload_lds16(const void* g, void* l) {
  __builtin_amdgcn_global_load_lds(
      (const __attribute__((address_space(1))) void*)g,
      (__attribute__((address_space(3))) void*)l, 16, 0, 0);
}

#define BAR()    __builtin_amdgcn_s_barrier()
#define VM12()   asm volatile("s_waitcnt vmcnt(12)" ::: "memory")
#define VM8()    asm volatile("s_waitcnt vmcnt(8)"  ::: "memory")
#define VM4()    asm volatile("s_waitcnt vmcnt(4)"  ::: "memory")
#define PRIO(x)  __builtin_amdgcn_s_setprio(x)
#define SCHED0() __builtin_amdgcn_sched_barrier(0)
#define MFMA(d, x, y) d = __builtin_amdgcn_mfma_f32_16x16x32_bf16(x, y, d, 0, 0, 0)

// ---- x fp32 -> bf16 ----
__global__ void cvt_x_kernel(const float* __restrict__ x, __bf16* __restrict__ xb, int n) {
  int i = (blockIdx.x * blockDim.x + threadIdx.x) * 8;
  if (i >= n) return;
  float4 f0 = *(const float4*)(x + i);
  float4 f1 = *(const float4*)(x + i + 4);
  bf16x8 v;
  v[0] = (__bf16)f0.x; v[1] = (__bf16)f0.y; v[2] = (__bf16)f0.z; v[3] = (__bf16)f0.w;
  v[4] = (__bf16)f1.x; v[5] = (__bf16)f1.y; v[6] = (__bf16)f1.z; v[7] = (__bf16)f1.w;
  *(bf16x8*)(xb + i) = v;
}

// ---- kernel [O][C][KW] fp32 -> Wt2 fragment-native bf16 ----
// elem idx = ((ks*32 + ob)*64 + l)*8 + j
//   col o = ob*16 + (l&15); k = ks*32 + ((l>>4)&3)*8 + j; c = k&511; kw = k>>9
__global__ void cvt_w_kernel(const float* __restrict__ k, __bf16* __restrict__ wt) {
  int idx = blockIdx.x * blockDim.x + threadIdx.x;   // 1,310,720
  if (idx >= 80 * 32 * 512) return;
  int j  = idx & 7;
  int l  = (idx >> 3) & 63;
  int t1 = idx >> 9;
  int ob = t1 & 31;
  int ks = t1 >> 5;
  int o  = ob * 16 + (l & 15);
  int kk = ks * 32 + ((l >> 4) & 3) * 8 + j;
  int c  = kk & 511, kw = kk >> 9;
  wt[idx] = (__bf16)k[(o * CIN + c) * 5 + kw];
}

// stage one A K-tile (128 rows x 64 bf16 = 16 KiB) into LDS buffer `buf` (literal)
#define STAGE(buf, kt) do { \
    char* d_ = (char*)Ab + ((buf) << 14); \
    gload_lds16(Xb + offA0 + (kt) * 64, d_ + dof0); \
    gload_lds16(Xb + offA1 + (kt) * 64, d_ + dof1); \
    gload_lds16(Xb + offA2 + (kt) * 64, d_ + dof2); \
    gload_lds16(Xb + offA3 + (kt) * 64, d_ + dof3); } while (0)

// load next-tile B fragments from global (L2-resident), 8 x dwordx4
#define LOADB(bn, Tn) do { \
    const char* p_ = Wglob + (size_t)(Tn) * 65536; \
    bn[0][0] = *(const bf16x8*)(p_ +     0); bn[0][1] = *(const bf16x8*)(p_ + 32768); \
    bn[1][0] = *(const bf16x8*)(p_ +  1024); bn[1][1] = *(const bf16x8*)(p_ + 33792); \
    bn[2][0] = *(const bf16x8*)(p_ +  2048); bn[2][1] = *(const bf16x8*)(p_ + 34816); \
    bn[3][0] = *(const bf16x8*)(p_ +  3072); bn[3][1] = *(const bf16x8*)(p_ + 35840); } while (0)

// one K-tile: prefetch B(T+1)->regs, stage A(T+2)->LDS buf `bufs` (literal),
// compute from buf `bufc` (literal); counted vmcnt + single barrier.
#define TILE(T, bc, bn, bufc, bufs) do { \
    const bool s1_ = (T) + 1 < NKT, s2_ = (T) + 2 < NKT; \
    if (s1_) LOADB(bn, (T) + 1); \
    if (s2_) STAGE(bufs, (T) + 2); \
    const char* Ac_ = Aw + ((bufc) << 14); \
    bf16x8 a_[4][2]; \
    _Pragma("unroll") \
    for (int mi = 0; mi < 4; ++mi) { \
      a_[mi][0] = *(const bf16x8*)(Ac_ + mi * 2048 + off0); \
      a_[mi][1] = *(const bf16x8*)(Ac_ + mi * 2048 + off1); \
    } \
    PRIO(1); \
    _Pragma("unroll") \
    for (int mi = 0; mi < 4; ++mi) \
      _Pragma("unroll") \
      for (int nj = 0; nj < 4; ++nj) { \
        MFMA(acc[mi][nj], a_[mi][0], bc[nj][0]); \
        MFMA(acc[mi][nj], a_[mi][1], bc[nj][1]); \
      } \
    PRIO(0); \
    SCHED0(); \
    if (s2_) { VM12(); } else if (s1_) { VM8(); } \
    if (s1_) BAR(); \
  } while (0)

__global__ __launch_bounds__(256, 2)
void tdnn_gemm_kernel(const __bf16* __restrict__ Xb, const __bf16* __restrict__ Wt2,
                      const float* __restrict__ bias, float* __restrict__ out) {
  // A only: 3 rotating K-tile buffers x 128 rows x 64 bf16 = 48 KiB
  // -> LDS permits 3 blocks/CU; allocator NOT constrained (launch_bounds .,2)
  __shared__ __bf16 Ab[3][128][64];

  const int tid  = threadIdx.x;
  const int wave = tid >> 6;
  const int lane = tid & 63;
  const int wr = wave >> 1;          // 0..1 : 64-row band
  const int wc = wave & 1;           // 0..1 : 64-col band

  // bijective XCD swizzle: 1992 = 8*249; consecutive swz share the A-panel
  int bid = blockIdx.x;
  int swz = (bid & 7) * 249 + (bid >> 3);
  const int m0 = (swz >> 2) * 128;
  const int n0 = (swz & 3) * 128;

  // ---- A staging offsets (pre-swizzled global source, linear LDS dest)
  int offA0, offA1, offA2, offA3, dof0, dof1, dof2, dof3;
  {
    int rr, ce, m, b, tt;
#define MKOFF(l, A, D) \
    rr = (l) * 32 + (tid >> 3); \
    ce = (((tid & 7) ^ (rr & 7)) << 3); \
    D  = ((l) * 256 + tid) * 16; \
    m = m0 + rr; b = m / TOUT; tt = m - b * TOUT; \
    A = (b * SEQ + tt) * CIN + ce;
    MKOFF(0, offA0, dof0)
    MKOFF(1, offA1, dof1)
    MKOFF(2, offA2, dof2)
    MKOFF(3, offA3, dof3)
#undef MKOFF
  }

  // ---- fragment read geometry (A from LDS, T2 read-side XOR)
  const int frow = lane & 15;
  const int fkb  = (lane >> 4) << 4;        // 0,16,32,48 bytes
  const int xorv = (frow & 7) << 4;
  const int off0 = fkb ^ xorv;              // k-slice 0
  const int off1 = (64 + fkb) ^ xorv;       // k-slice 1
  const char* Aw = (const char*)Ab + (wr * 64 + frow) * 128;

  // ---- B fragment-native global base for this wave
  const int obW = (n0 >> 4) + wc * 4;
  const char* Wglob = (const char*)Wt2 + obW * 1024 + lane * 16;

  f32x4 acc[4][4];
  const f32x4 z = {0.f, 0.f, 0.f, 0.f};
#pragma unroll
  for (int i = 0; i < 4; i++)
#pragma unroll
    for (int j = 0; j < 4; j++) acc[i][j] = z;

  bf16x8 bA[4][2], bB[4][2];

  // ---- prologue: B(0)->bA, stage A(0)->buf0, A(1)->buf1; drain through A(0)
  LOADB(bA, 0);
  STAGE(0, 0);
  STAGE(1, 1);
  VM4();       // in-order: drains B(0)x8 + A(0)x4, leaves A(1)x4 in flight
  BAR();

  // buffer of tile T = T%3, all indices compile-time (period 6 = lcm(2,3)).
  // Liveness: tile T stages (T+2)%3 which tile T-1 finished reading before
  // its end-of-tile barrier; VM12 in tile T+1 drains A(T+2) before its BAR.
  for (int T = 0; T < 36; T += 6) {
    TILE(T,     bA, bB, 0, 2);
    TILE(T + 1, bB, bA, 1, 0);
    TILE(T + 2, bA, bB, 2, 1);
    TILE(T + 3, bB, bA, 0, 2);
    TILE(T + 4, bA, bB, 1, 0);
    TILE(T + 5, bB, bA, 2, 1);
  }
  TILE(36, bA, bB, 0, 2);
  TILE(37, bB, bA, 1, 0);
  TILE(38, bA, bB, 2, 1);
  TILE(39, bB, bA, 0, 2);

  // ---- epilogue: bias + relu + store. C/D map: col=lane&15, row=(lane>>4)*4+reg
  const int ccol = lane & 15;
  const int crow = (lane >> 4) * 4;
  float bv[4];
#pragma unroll
  for (int nj = 0; nj < 4; ++nj)
    bv[nj] = bias[n0 + wc * 64 + nj * 16 + ccol];

#pragma unroll
  for (int mi = 0; mi < 4; ++mi) {
    const int mrow = m0 + wr * 64 + mi * 16 + crow;
#pragma unroll
    for (int nj = 0; nj < 4; ++nj) {
      const int ocol = n0 + wc * 64 + nj * 16 + ccol;
#pragma unroll
      for (int j = 0; j < 4; ++j) {
        float v = acc[mi][nj][j] + bv[nj];
        v = v > 0.f ? v : 0.f;
        out[(size_t)(mrow + j) * COUT + ocol] = v;
      }
    }
  }
}

extern "C" void kernel_launch(void* const* d_in, const int* in_sizes, int n_in,
                              void* d_out, int out_size, void* d_ws, size_t ws_size,
                              hipStream_t stream) {
  const float* x      = (const float*)d_in[0];   // [64,1000,512] fp32
  const float* kernel = (const float*)d_in[1];   // [512,512,5]   fp32
  const float* bias   = (const float*)d_in[2];   // [512]         fp32
  float* out          = (float*)d_out;           // [64,996,512]  fp32

  __bf16* xb  = (__bf16*)d_ws;
  __bf16* wt2 = (__bf16*)((char*)d_ws + (size_t)BATCH * SEQ * CIN * 2);

  const int nx = BATCH * SEQ * CIN;              // 32,768,000
  cvt_x_kernel<<<nx / 8 / 256, 256, 0, stream>>>(x, xb, nx);
  cvt_w_kernel<<<(80 * 32 * 512 + 255) / 256, 256, 0, stream>>>(kernel, wt2);
  tdnn_gemm_kernel<<<NWG, 256, 0, stream>>>(xb, wt2, bias, out);
}